// Round 4
// baseline (350.172 us; speedup 1.0000x reference)
//
#include <hip/hip_runtime.h>
#include <math.h>

// DTW 2048x2048, squared-diff cost, out = sqrt(DTW[2047][2047]).
//
// NW=4 waves (256 thr) on one CU, R=8 rows/lane, lanes skewed 2 cols apart.
// Lane l of wave w owns rows 8*(64w+l)..+7, split into group A (rows 0-3,
// col a = tau - 2l) and group B (rows 4-7, col a-1). Two independent 4-row
// min3+fma chains per step (ILP 2, ~36cy chain).
// Cross-lane: u = DPP wave_shr:1 of v7 (lane l-1's row7 lands exactly one
// step before lane l needs it under skew-2). y is delivered by a second DPP
// pipeline (pair yP,yQ shifted every 2 steps, lane 0 injects uniform y).
// All non-write LDS traffic is wave-uniform and batched: 16 ds_read_b128
// per 64-step block into registers (one amortized wait, ~2cy/step).
// Ring rows unwrapped (2368 slots, +128 offset); all lanes store row7 every
// step, lane 63 (true strip boundary) writes each column last; DSKEW=192
// with barriers every 64 steps guarantees producer block completes before
// the consumer's block-top batched read of the same columns.

#define NLEN  2048
#define NW    4
#define CSTEP 64
#define DSKEW 192
#define RROW  2368
#define GTOT  2752          // (NW-1)*DSKEW + 2174 rounded up to 64
#define INFV  1e30f

__device__ __forceinline__ float dpp_shr1(float v, float inj) {
    int r = __builtin_amdgcn_update_dpp(
        __builtin_bit_cast(int, inj), __builtin_bit_cast(int, v),
        0x138 /*wave_shr:1*/, 0xF, 0xF, false /*keep old in lane 0*/);
    return __builtin_bit_cast(float, r);
}
__device__ __forceinline__ float min3f(float a, float b, float c) {
    return fminf(fminf(a, b), c);
}
__device__ __forceinline__ float comp4(float4 v, int k) {
    return k == 0 ? v.x : k == 1 ? v.y : k == 2 ? v.z : v.w;
}

__global__ __launch_bounds__(256, 1) void dtw_kernel(const float* __restrict__ X,
                                                     const float* __restrict__ Y,
                                                     float* __restrict__ out) {
    __shared__ __align__(16) float yS[NLEN];
    __shared__ __align__(16) float ring[(NW + 1) * RROW];

    const int tid  = threadIdx.x;
    const int w    = tid >> 6;
    const int lane = tid & 63;

    {
        const float4* Y4 = (const float4*)Y;
        float4* y4 = (float4*)yS;
        y4[tid]       = Y4[tid];
        y4[tid + 256] = Y4[tid + 256];
    }
    for (int k = tid; k < RROW; k += 256) ring[k] = INFV;  // virtual row -1
    __syncthreads();

    float x0, x1, x2, x3, x4, x5, x6, x7;
    {
        const float4 xa = *(const float4*)&X[tid * 8];
        const float4 xb = *(const float4*)&X[tid * 8 + 4];
        x0 = xa.x; x1 = xa.y; x2 = xa.z; x3 = xa.w;
        x4 = xb.x; x5 = xb.y; x6 = xb.z; x7 = xb.w;
    }

    float v0 = INFV, v1 = INFV, v2 = INFV, v3 = INFV;
    float v4 = INFV, v5 = INFV, v6 = INFV, v7 = INFV;
    float v3m1 = INFV;                         // row3 value one B-col back
    float uprev = (tid == 0) ? 0.0f : INFV;    // DTW[-1][-1]=0 seed
    float yP = INFV, yQ = INFV, ym = INFV;     // y DPP pipeline

    const float* ringR = &ring[w * RROW + 128];
    float*       ringW = &ring[(w + 1) * RROW + 128];

    for (int gb = 0; gb < GTOT; gb += CSTEP) {
        const int tau0 = gb - w * DSKEW;

        if (tau0 >= 2 * CSTEP && tau0 + CSTEP <= NLEN) {
            // ================= steady state =================
            const float4* rp4 = (const float4*)(ringR + tau0);
            const float4* yp4 = (const float4*)(yS + tau0);
            float* wp = ringW + (tau0 - 2 * lane - 1);

            float4 rr[16], yy[16];
            #pragma unroll
            for (int q = 0; q < 16; ++q) { rr[q] = rp4[q]; yy[q] = yp4[q]; }

            #pragma unroll
            for (int s = 0; s < CSTEP; ++s) {
                const float ru_s = comp4(rr[s >> 2], s & 3);
                if ((s & 1) == 0) {
                    ym = yQ;
                    yP = dpp_shr1(yP, comp4(yy[s >> 2], s & 3));
                    yQ = dpp_shr1(yQ, comp4(yy[s >> 2], (s & 3) + 1));
                }
                const float yA = ((s & 1) == 0) ? yP : yQ;
                const float yB = ((s & 1) == 0) ? ym : yP;
                const float u  = dpp_shr1(v7, ru_s);
                // group B: rows 4-7 at col a-1 (uses pre-update v3, v3m1)
                float d4 = x4 - yB; float nv4 = fmaf(d4, d4, min3f(v4, v3m1, v3));
                float d5 = x5 - yB; float nv5 = fmaf(d5, d5, min3f(v5, v4, nv4));
                float d6 = x6 - yB; float nv6 = fmaf(d6, d6, min3f(v6, v5, nv5));
                float d7 = x7 - yB; float nv7 = fmaf(d7, d7, min3f(v7, v6, nv6));
                // group A: rows 0-3 at col a
                float d0 = x0 - yA; float nv0 = fmaf(d0, d0, min3f(v0, uprev, u));
                float d1 = x1 - yA; float nv1 = fmaf(d1, d1, min3f(v1, v0, nv0));
                float d2 = x2 - yA; float nv2 = fmaf(d2, d2, min3f(v2, v1, nv1));
                float d3 = x3 - yA; float nv3 = fmaf(d3, d3, min3f(v3, v2, nv2));
                wp[s] = nv7;
                v3m1 = v3;
                v0 = nv0; v1 = nv1; v2 = nv2; v3 = nv3;
                v4 = nv4; v5 = nv5; v6 = nv6; v7 = nv7;
                uprev = u;
            }
        } else if (tau0 >= 0 && tau0 <= 2112) {
            // ================= ramp up / down =================
            for (int s = 0; s < CSTEP; ++s) {
                const int t = tau0 + s;
                const int a = t - 2 * lane;
                const float ru_s = ringR[t];
                if ((s & 1) == 0) {
                    ym = yQ;
                    yP = dpp_shr1(yP, yS[t & (NLEN - 1)]);
                    yQ = dpp_shr1(yQ, yS[(t + 1) & (NLEN - 1)]);
                }
                const float yA = ((s & 1) == 0) ? yP : yQ;
                const float yB = ((s & 1) == 0) ? ym : yP;
                const float u  = dpp_shr1(v7, ru_s);
                float d4 = x4 - yB; float nv4 = fmaf(d4, d4, min3f(v4, v3m1, v3));
                float d5 = x5 - yB; float nv5 = fmaf(d5, d5, min3f(v5, v4, nv4));
                float d6 = x6 - yB; float nv6 = fmaf(d6, d6, min3f(v6, v5, nv5));
                float d7 = x7 - yB; float nv7 = fmaf(d7, d7, min3f(v7, v6, nv6));
                float d0 = x0 - yA; float nv0 = fmaf(d0, d0, min3f(v0, uprev, u));
                float d1 = x1 - yA; float nv1 = fmaf(d1, d1, min3f(v1, v0, nv0));
                float d2 = x2 - yA; float nv2 = fmaf(d2, d2, min3f(v2, v1, nv1));
                float d3 = x3 - yA; float nv3 = fmaf(d3, d3, min3f(v3, v2, nv2));
                const int b = a - 1;
                if (b >= 0 && b < NLEN) {
                    v4 = nv4; v5 = nv5; v6 = nv6; v7 = nv7;
                    ringW[b] = nv7;
                    if (b == NLEN - 1 && w == NW - 1 && lane == 63)
                        out[0] = sqrtf(nv7);
                }
                if (a >= 0 && a < NLEN) {
                    v3m1 = v3;
                    v0 = nv0; v1 = nv1; v2 = nv2; v3 = nv3;
                }
                uprev = u;
            }
        }
        __syncthreads();
    }
}

extern "C" void kernel_launch(void* const* d_in, const int* in_sizes, int n_in,
                              void* d_out, int out_size, void* d_ws, size_t ws_size,
                              hipStream_t stream) {
    const float* x = (const float*)d_in[0];
    const float* y = (const float*)d_in[1];
    (void)in_sizes; (void)n_in; (void)out_size; (void)d_ws; (void)ws_size;
    dtw_kernel<<<1, 256, 0, stream>>>(x, y, (float*)d_out);
}

// Round 5
// 198.050 us; speedup vs baseline: 1.7681x; 1.7681x over previous
//
#include <hip/hip_runtime.h>
#include <math.h>

// DTW 2048x2048, squared-diff cost, out = sqrt(DTW[2047][2047]).
//
// Skew-1 wave pipeline, NW=4 waves (256 thr) on one CU, R=8 rows/lane.
// Lane l of wave w owns rows 8*(64w+l)..+7; at wave-step t it computes
// column j = t - l for its 8 rows (serial min3+fma chain, ~68cy).
//
// Zero per-step LDS reads: per 64-step block each wave does TWO coalesced
// ds_read_b32 (y[tau0+lane], ring[tau0+lane]); per step, v_readlane(blk, s)
// (compile-time s) yields the wave-uniform y[tau0+s] / ring[tau0+s], which
// are injected into two DPP wave_shr:1 conveyors:
//   yconv: lane l holds y[t-l] (its column's y)
//   u    : lane l holds lane l-1's row-7 value (above/diag input); lane 0
//          gets the ring injection (row above the strip).
// There is nothing for the compiler to sink back to LDS (rounds 3/4 lesson:
// batched LDS->reg arrays get SSA'd away; VGPR count is the tell).
//
// Guard-free: INFV=1e30 absorbs adds (1e30 + d^2 == 1e30 in fp32), so
// inactive-lane "commits" are idempotent; OOB ring writes (j<0 on ramp-in,
// j>=2048 on ramp-out) land in pad regions. Every block tau0 in [0,2048]
// runs the identical unrolled body -- no ramp/steady split, no per-step
// guards. Output is stored at the unique step (tau0==2048, s==62, w=3,
// lane 63) where j==2047.
//
// Ring: unwrapped rows, PAD=64 left pad, cols -64..2111 valid. All lanes
// write their row-7 value each step; lane 63 (true strip boundary) writes
// each column last within the wave, and DSKEW=128 + barrier every 64 steps
// guarantees the producer completed wave-step tau0+127 >= j+63 for every
// column j <= tau0+63 the consumer's block-top read touches.

#define NLEN  2048
#define NW    4
#define CSTEP 64
#define DSKEW 128
#define PAD   64
#define RROW  (PAD + 2112)              // writes/reads span cols -64..2111
#define GTOT  2496                      // last block: w=3, tau0=2048
#define INFV  1e30f

__device__ __forceinline__ float dpp_shr1(float v, float inj) {
    int r = __builtin_amdgcn_update_dpp(
        __builtin_bit_cast(int, inj), __builtin_bit_cast(int, v),
        0x138 /*wave_shr:1*/, 0xF, 0xF, false /*lane0 keeps old=inj*/);
    return __builtin_bit_cast(float, r);
}
__device__ __forceinline__ float rdlane(float v, int l) {
    return __builtin_bit_cast(float,
        __builtin_amdgcn_readlane(__builtin_bit_cast(int, v), l));
}
__device__ __forceinline__ float min3f(float a, float b, float c) {
    return fminf(fminf(a, b), c);
}

__global__ __launch_bounds__(256, 1) void dtw_kernel(const float* __restrict__ X,
                                                     const float* __restrict__ Y,
                                                     float* __restrict__ out) {
    __shared__ __align__(16) float yS[NLEN];
    __shared__ float ring[(NW + 1) * RROW];

    const int tid  = threadIdx.x;
    const int w    = tid >> 6;
    const int lane = tid & 63;

    {
        const float4* Y4 = (const float4*)Y;
        float4* y4 = (float4*)yS;
        y4[tid]       = Y4[tid];
        y4[tid + 256] = Y4[tid + 256];
    }
    // Entire ring INFV: virtual row -1, pads, and unwritten tails.
    for (int k = tid; k < (NW + 1) * RROW; k += 256) ring[k] = INFV;
    __syncthreads();

    float x0, x1, x2, x3, x4, x5, x6, x7;
    {
        const float4 xa = *(const float4*)&X[tid * 8];
        const float4 xb = *(const float4*)&X[tid * 8 + 4];
        x0 = xa.x; x1 = xa.y; x2 = xa.z; x3 = xa.w;
        x4 = xb.x; x5 = xb.y; x6 = xb.z; x7 = xb.w;
    }

    float v0 = INFV, v1 = INFV, v2 = INFV, v3 = INFV;
    float v4 = INFV, v5 = INFV, v6 = INFV, v7 = INFV;
    float uprev = (tid == 0) ? 0.0f : INFV;   // DTW[-1][-1]=0 seed
    float yconv = 0.0f;                       // y DPP conveyor

    const float* ringR = ring + w * RROW + PAD;
    float*       ringW = ring + (w + 1) * RROW + PAD;

    for (int gb = 0; gb < GTOT; gb += CSTEP) {
        const int tau0 = gb - w * DSKEW;

        if (tau0 >= 0 && tau0 <= NLEN) {
            int yi = tau0 + lane;                    // clamp for tau0==2048
            if (yi >= NLEN) yi = NLEN - 1;
            const float yblk = yS[yi];               // 1 coalesced ds_read
            const float rblk = ringR[tau0 + lane];   // 1 coalesced ds_read
            float* wp = ringW + (tau0 - lane);
            const bool isout = (tau0 == NLEN) & (w == NW - 1) & (lane == 63);

            #pragma unroll
            for (int s = 0; s < CSTEP; ++s) {
                const float yu = rdlane(yblk, s);    // y[tau0+s] (scalar)
                const float ru = rdlane(rblk, s);    // ring[tau0+s] (scalar)
                yconv = dpp_shr1(yconv, yu);         // lane l: y[tau0+s-l]
                const float u = dpp_shr1(v7, ru);    // above value
                float d0 = x0 - yconv; float nv0 = fmaf(d0, d0, min3f(v0, uprev, u));
                float d1 = x1 - yconv; float nv1 = fmaf(d1, d1, min3f(v1, v0, nv0));
                float d2 = x2 - yconv; float nv2 = fmaf(d2, d2, min3f(v2, v1, nv1));
                float d3 = x3 - yconv; float nv3 = fmaf(d3, d3, min3f(v3, v2, nv2));
                float d4 = x4 - yconv; float nv4 = fmaf(d4, d4, min3f(v4, v3, nv3));
                float d5 = x5 - yconv; float nv5 = fmaf(d5, d5, min3f(v5, v4, nv4));
                float d6 = x6 - yconv; float nv6 = fmaf(d6, d6, min3f(v6, v5, nv5));
                float d7 = x7 - yconv; float nv7 = fmaf(d7, d7, min3f(v7, v6, nv6));
                wp[s] = nv7;
                uprev = u;
                v0 = nv0; v1 = nv1; v2 = nv2; v3 = nv3;
                v4 = nv4; v5 = nv5; v6 = nv6; v7 = nv7;
                if (s == 62 && isout) out[0] = sqrtf(nv7);  // j == 2047
            }
        }
        __syncthreads();
    }
}

extern "C" void kernel_launch(void* const* d_in, const int* in_sizes, int n_in,
                              void* d_out, int out_size, void* d_ws, size_t ws_size,
                              hipStream_t stream) {
    const float* x = (const float*)d_in[0];
    const float* y = (const float*)d_in[1];
    (void)in_sizes; (void)n_in; (void)out_size; (void)d_ws; (void)ws_size;
    dtw_kernel<<<1, 256, 0, stream>>>(x, y, (float*)d_out);
}